// Round 11
// baseline (206.668 us; speedup 1.0000x reference)
//
#include <hip/hip_runtime.h>
#include <stdint.h>

typedef int int32x4  __attribute__((ext_vector_type(4)));
typedef int int32x16 __attribute__((ext_vector_type(16)));

constexpr int K_DIM = 4096;   // D_IN
constexpr int N_DIM = 4096;   // D_OUT
constexpr float QMAXF = 127.0f;

// ---------------------------------------------------------------------------
// Kernel 1: per-token dynamic absmax quantization
// ---------------------------------------------------------------------------
__global__ __launch_bounds__(256) void quant_rows(const float* __restrict__ x,
                                                  int8_t* __restrict__ q,
                                                  float* __restrict__ scales) {
    const int row = blockIdx.x;
    const int tid = threadIdx.x;
    const size_t base = (size_t)row * K_DIM;

    const float4* xv = reinterpret_cast<const float4*>(x + base);
    float4 v[4];
#pragma unroll
    for (int i = 0; i < 4; ++i) v[i] = xv[tid + 256 * i];

    float m = 0.0f;
#pragma unroll
    for (int i = 0; i < 4; ++i)
        m = fmaxf(m, fmaxf(fmaxf(fabsf(v[i].x), fabsf(v[i].y)),
                           fmaxf(fabsf(v[i].z), fabsf(v[i].w))));
#pragma unroll
    for (int off = 32; off > 0; off >>= 1) m = fmaxf(m, __shfl_xor(m, off));

    __shared__ float wmax[4];
    if ((tid & 63) == 0) wmax[tid >> 6] = m;
    __syncthreads();
    const float am = fmaxf(fmaxf(wmax[0], wmax[1]), fmaxf(wmax[2], wmax[3]));
    const float scale = fmaxf(am * (1.0f / 127.0f), 1e-8f);
    if (tid == 0) scales[row] = scale;
    const float inv = 1.0f / scale;

    int* qw = reinterpret_cast<int*>(q + base);
#pragma unroll
    for (int i = 0; i < 4; ++i) {
        float f0 = fminf(QMAXF, fmaxf(-QMAXF, rintf(v[i].x * inv)));
        float f1 = fminf(QMAXF, fmaxf(-QMAXF, rintf(v[i].y * inv)));
        float f2 = fminf(QMAXF, fmaxf(-QMAXF, rintf(v[i].z * inv)));
        float f3 = fminf(QMAXF, fmaxf(-QMAXF, rintf(v[i].w * inv)));
        int b0 = ((int)f0) & 255, b1 = ((int)f1) & 255;
        int b2 = ((int)f2) & 255, b3 = ((int)f3) & 255;
        qw[tid + 256 * i] = b0 | (b1 << 8) | (b2 << 16) | (b3 << 24);
    }
}

// ---------------------------------------------------------------------------
// Kernel 2: pack int32 weight buffer -> int8
// ---------------------------------------------------------------------------
__global__ __launch_bounds__(256) void pack_w(const int* __restrict__ w,
                                              int8_t* __restrict__ w8) {
    const int idx = blockIdx.x * 256 + threadIdx.x;
    const int4 v = reinterpret_cast<const int4*>(w)[idx];
    int packed = (v.x & 255) | ((v.y & 255) << 8) | ((v.z & 255) << 16) | ((v.w & 255) << 24);
    reinterpret_cast<int*>(w8)[idx] = packed;
}

// ---------------------------------------------------------------------------
// Kernel 3: int8 GEMM, mfma_i32_32x32x32_i8, K-MAJOR SEGMENTED LDS LAYOUT.
// r6/r10 skeleton: 256x256 tile, BKB=128, 8 waves (2Mx4N of 128x64), dbuf-2
// (128 KB), 2 barriers + counted vmcnt per tile, barrier-free interior of 8
// sub-phases {<=1 LDFRAG | 4 dependent-ks MFMA}.
//
// LDS layout (round-11 fix): tile = [ks(4)][rowblk(8)][r(32)][gr(2)] x 16B.
// Empirical conflict rule (r2-r8 = 0 conflicts; r9/r10 scattered = 1.26e7):
// a wave ds_read_b128 is conflict-free iff its 64 lanes form a permutation
// of ONE contiguous 1024-B-aligned block. Here fragment (mi|ni, ks) reads
// block ks*8192 + blk*1024, lane addr + l31*32 + lh*16 -> exact linear
// permutation. No XOR swizzle anywhere.
//
// Staging (rule 21: linear LDS dest, per-lane global source): GLL line
// j (0..3) stages ks=j, rowblk=wave: dst = j*8192 + wave*1024 (+lane*16 HW);
// lane l: dest unit (r,gr) = (l>>1, l&1) => global row = wave*32 + (l>>1),
// kbyte = t*128 + j*32 + (l&1)*16.
//
// GLL ledger (verified r9/r10): A(t+1)x4 lines at tile top after WAR
// barrier -> vmcnt(4) guarantees tile t landed, leaves A(t+1) in flight;
// B(t+1)x4 at sub-phase (2,1). Tail t=NT-1: vmcnt(0).
// C/D 32x32 (verified r9/r10): col=lane&31, row=(reg&3)+8*(reg>>2)+4*(lane>>5).
// ---------------------------------------------------------------------------
constexpr int BM = 256, BN = 256, BKB = 128;
constexpr int NT = K_DIM / BKB;    // 32 K-tiles

#define GLL(src, dst)                                                          \
    __builtin_amdgcn_global_load_lds(                                          \
        (const __attribute__((address_space(1))) unsigned int*)(src),          \
        (__attribute__((address_space(3))) unsigned int*)(dst), 16, 0, 0)

#define MFMA32(a, b, c) __builtin_amdgcn_mfma_i32_32x32x32_i8((a), (b), (c), 0, 0, 0)

// 4 dependent-ks MFMAs on one accumulator quadrant, setprio-wrapped
#define MFMA4(ACC, AF, BF)                                                     \
    {                                                                          \
        __builtin_amdgcn_s_setprio(1);                                         \
        ACC = MFMA32(AF[0], BF[0], ACC);                                       \
        ACC = MFMA32(AF[1], BF[1], ACC);                                       \
        ACC = MFMA32(AF[2], BF[2], ACC);                                       \
        ACC = MFMA32(AF[3], BF[3], ACC);                                       \
        __builtin_amdgcn_s_setprio(0);                                         \
    }

// load one 4-ks fragment set; P already includes lane offset + block base,
// OFF = (mi or ni)*1024; ks stride = 8192.
#define LDFRAG(DST, P, OFF)                                                    \
    DST[0] = *(const int32x4*)((P) + (OFF));                                   \
    DST[1] = *(const int32x4*)((P) + (OFF) + 8192);                            \
    DST[2] = *(const int32x4*)((P) + (OFF) + 16384);                           \
    DST[3] = *(const int32x4*)((P) + (OFF) + 24576);

__global__ __launch_bounds__(512, 2) void w8a8_gemm256(
        const int8_t* __restrict__ A, const int8_t* __restrict__ B,
        const float* __restrict__ asc, const float* __restrict__ wsc,
        float* __restrict__ C, int M) {
    extern __shared__ int8_t lds[];   // 128 KB: A dbuf @0, B dbuf @65536

    const int tid  = threadIdx.x;
    const int lane = tid & 63;
    const int wave = tid >> 6;

    // XCD-aware bijective swizzle (nwg = 512, divisible by 8)
    const int nwg = gridDim.x;
    const int bid = blockIdx.x;
    const int swz = (bid & 7) * (nwg >> 3) + (bid >> 3);
    const int NB  = N_DIM / BN;               // 16
    const int brow = (swz / NB) * BM;
    const int bcol = (swz % NB) * BN;

    const int wm = wave >> 2;                 // 0..1
    const int wn = wave & 3;                  // 0..3
    const int l31 = lane & 31;
    const int lh  = lane >> 5;                // 0..1

    // ---- staging: per-lane global source for GLL line j of tile t:
    //   src = g{A,B} + t*128 + j*32 ; dst = tilebuf + j*8192 + wave*1024
    const int rowch = wave * 32 + (lane >> 1);
    const int g16   = (lane & 1) * 16;
    const int8_t* gA = A + (size_t)(brow + rowch) * K_DIM + g16;
    const int8_t* gB = B + (size_t)(bcol + rowch) * K_DIM + g16;
    const int segb  = wave * 1024;            // wave-uniform LDS base

    // ---- compute-side lane offsets (linear, no swizzle) ----
    const int laneoff = l31 * 32 + lh * 16;
    const int aoff = wm * 4096 + laneoff;     // wm*4 rowblks
    const int boff = wn * 2048 + laneoff;     // wn*2 colblks

    int32x16 acc[4][2];
#pragma unroll
    for (int i = 0; i < 4; ++i)
#pragma unroll
        for (int j = 0; j < 2; ++j)
#pragma unroll
            for (int e = 0; e < 16; ++e) acc[i][j][e] = 0;

    // ---- prologue: stage tile 0 fully ----
#pragma unroll
    for (int c = 0; c < 4; ++c) {
        GLL(gA + c * 32, lds + c * 8192 + segb);
        GLL(gB + c * 32, lds + 65536 + c * 8192 + segb);
    }
    asm volatile("s_waitcnt vmcnt(0)" ::: "memory");
    __builtin_amdgcn_s_barrier();

    int32x4 af[2][4], bf[2][4];

    for (int t = 0; t < NT; ++t) {
        const int8_t* Ab = lds + (t & 1) * 32768 + aoff;
        const int8_t* Bb = lds + 65536 + (t & 1) * 32768 + boff;
        int8_t* dA = lds + ((t + 1) & 1) * 32768;
        int8_t* dB = lds + 65536 + ((t + 1) & 1) * 32768;
        const bool pf = (t + 1 < NT);
        const int kk = (t + 1) * BKB;

        // B1: WAR fence — all waves done reading buf[(t+1)&1]
        __builtin_amdgcn_s_barrier();
        if (pf) {
#pragma unroll
            for (int c = 0; c < 4; ++c)
                GLL(gA + kk + c * 32, dA + c * 8192 + segb);
            asm volatile("s_waitcnt vmcnt(4)" ::: "memory");   // tile t landed
        } else {
            asm volatile("s_waitcnt vmcnt(0)" ::: "memory");
        }
        // B2: staging visibility block-wide
        __builtin_amdgcn_s_barrier();

        // tile-top reads: A[0] and B[0]
        LDFRAG(af[0], Ab, 0);
        LDFRAG(bf[0], Bb, 0);

        // ---- 8 sub-phases, barrier-free; compiler inserts minimal lgkm waits
        // ph(0,0): issue B[1]; MFMA m0n0
        LDFRAG(bf[1], Bb, 1024);
        MFMA4(acc[0][0], af[0], bf[0]);

        // ph(0,1): issue A[1]; MFMA m0n1
        LDFRAG(af[1], Ab, 1024);
        MFMA4(acc[0][1], af[0], bf[1]);

        // ph(1,0): issue A[2] -> af[0]; MFMA m1n0
        LDFRAG(af[0], Ab, 2048);
        MFMA4(acc[1][0], af[1], bf[0]);

        // ph(1,1): MFMA m1n1
        MFMA4(acc[1][1], af[1], bf[1]);

        // ph(2,0): issue A[3] -> af[1]; MFMA m2n0
        LDFRAG(af[1], Ab, 3072);
        MFMA4(acc[2][0], af[0], bf[0]);

        // ph(2,1): GLL B(t+1); MFMA m2n1
        if (pf) {
#pragma unroll
            for (int c = 0; c < 4; ++c)
                GLL(gB + kk + c * 32, dB + c * 8192 + segb);
        }
        MFMA4(acc[2][1], af[0], bf[1]);

        // ph(3,0) / ph(3,1)
        MFMA4(acc[3][0], af[1], bf[0]);
        MFMA4(acc[3][1], af[1], bf[1]);
    }

    // ---- epilogue: dequant + fp16-round
    // C/D 32x32: col = lane&31, row = (reg&3) + 8*(reg>>2) + 4*(lane>>5)
#pragma unroll
    for (int ni = 0; ni < 2; ++ni) {
        const int col = bcol + wn * 64 + ni * 32 + l31;
        const float ws = wsc[col];
#pragma unroll
        for (int mi = 0; mi < 4; ++mi) {
            const int rowb = brow + wm * 128 + mi * 32 + 4 * lh;
#pragma unroll
            for (int r = 0; r < 16; ++r) {
                const int row = rowb + (r & 3) + 8 * (r >> 2);
                float o = (float)acc[mi][ni][r] * asc[row] * ws;
                o = (float)(_Float16)o;   // emulate reference's fp16 cast
                C[(size_t)row * N_DIM + col] = o;
            }
        }
    }
}

// ---------------------------------------------------------------------------
extern "C" void kernel_launch(void* const* d_in, const int* in_sizes, int n_in,
                              void* d_out, int out_size, void* d_ws, size_t ws_size,
                              hipStream_t stream) {
    const float* x   = (const float*)d_in[0];   // [M][K], fp16-valued f32
    const int*   w   = (const int*)d_in[1];     // [N][K] int32 (int8-valued)
    const float* wsc = (const float*)d_in[2];   // [N]
    float* out = (float*)d_out;                 // [M][N] (fp16-valued f32)

    const int K = K_DIM;
    const int M = in_sizes[0] / K;              // 8192
    const int N = N_DIM;

    int8_t* q   = (int8_t*)d_ws;                               // M*K  = 32 MB
    int8_t* w8  = (int8_t*)d_ws + (size_t)M * K;               // N*K  = 16 MB
    float*  asc = (float*)((char*)d_ws + (size_t)M * K + (size_t)N * K);

    quant_rows<<<M, 256, 0, stream>>>(x, q, asc);
    pack_w<<<(N * (K / 4)) / 256, 256, 0, stream>>>(w, w8);
    const int grid = (M / BM) * (N / BN);       // 512
    w8a8_gemm256<<<grid, 512, 131072, stream>>>(q, w8, asc, wsc, out, M);
}